// Round 18
// baseline (262.702 us; speedup 1.0000x reference)
//
#include <hip/hip_runtime.h>
#include <hip/hip_bf16.h>

#define B 8
#define N 8192
#define E 65536
#define FIN 64
#define H 128
#define OUTD 256
#define NLAYER 3
#define EPS 1e-5f
#define NCHUNK 128               // pool chunks per batch (one per 64-row fused block)
#define NNODE (B * N)            // 65536 rows
#define KSTEPS 8                 // 2 groups x 4 k-steps of K=32 (xh*sWhi, nh*nWhi)
#define BPL (KSTEPS * 8 * 512)   // Bp ushort elems per layer
#define INSTEPS 6                // inproj: 3 groups x 2 k-steps (fh*Whi, fl*Whi, fh*Wlo)
#define ELLW 32                  // max incoming edges/node (Poisson(8): P(>32) ~ 2e-11)
#define PREPN (NLAYER * KSTEPS * 8 + INSTEPS * 8)   // 240 prep blocks
#define ZBLK 256                 // ecnt-zero blocks (int4 x 64 lanes x 256 = 65536 ints)
#define FILLB 512                // ELL-fill blocks (4 edges/thread)

#define AS1 __attribute__((address_space(1)))
#define AS3 __attribute__((address_space(3)))

typedef float f32x4 __attribute__((ext_vector_type(4)));
typedef __bf16 bf16x8 __attribute__((ext_vector_type(8)));

__device__ __forceinline__ float b2f(unsigned short u) {
    union { float f; unsigned int i; } c; c.i = ((unsigned int)u) << 16; return c.f;
}
__device__ __forceinline__ unsigned short f2b(float f) {
    __hip_bfloat16 h = __float2bfloat16(f);          // RTNE
    return *reinterpret_cast<unsigned short*>(&h);
}

// ---------------- weight pre-pack + ecnt zeroing (one node) ----------------
__global__ void k_prep(const float* __restrict__ selfW, const float* __restrict__ neighW,
                       const float* __restrict__ inW,
                       unsigned short* __restrict__ Bp, unsigned short* __restrict__ Bpi,
                       int* __restrict__ ecnt) {
    const int idx = blockIdx.x;
    const int lane = threadIdx.x;
    const int quad = lane >> 4, col = lane & 15;
    if (idx >= PREPN) {
        int4 z; z.x = 0; z.y = 0; z.z = 0; z.w = 0;
        ((int4*)ecnt)[(size_t)(idx - PREPN) * 64 + lane] = z;
        return;
    }
    if (idx < NLAYER * KSTEPS * 8) {
        const int t = idx & 7;
        const int s = (idx >> 3) % KSTEPS;
        const int l = idx / (KSTEPS * 8);
        const float* W = (((s >> 2) == 0) ? selfW : neighW) + (size_t)l * H * H;
        const int n = t * 16 + col;
        unsigned short* dst = Bp + ((size_t)(l * KSTEPS + s) * 8 + t) * 512 + lane * 8;
        #pragma unroll
        for (int j = 0; j < 8; ++j)
            dst[j] = f2b(W[((s & 3) * 32 + quad * 8 + j) * H + n]);
    } else {
        const int idx2 = idx - NLAYER * KSTEPS * 8;
        const int t = idx2 & 7;
        const int s = idx2 >> 3;                     // 0..5
        const bool lo = ((s >> 1) == 2);
        const int n = t * 16 + col;
        unsigned short* dst = Bpi + ((size_t)(s * 8 + t)) * 512 + lane * 8;
        #pragma unroll
        for (int j = 0; j < 8; ++j) {
            const float w = inW[((s & 1) * 32 + quad * 8 + j) * H + n];
            const unsigned short hi = f2b(w);
            dst[j] = lo ? f2b(w - b2f(hi)) : hi;
        }
    }
}

// ---------------- fat kernel: inproj (blocks 0..1023) || ELL fill (blocks 1024..1535, 4 edges/thread) ----------------
__global__ __launch_bounds__(256) void k_front(const float* __restrict__ feats,
                                               const unsigned short* __restrict__ Bpi,
                                               const float* __restrict__ bias,
                                               unsigned short* __restrict__ xh,
                                               const int* __restrict__ ei,
                                               const float* __restrict__ emask,
                                               int* __restrict__ ecnt,
                                               unsigned int* __restrict__ ell) {
    const int tid = threadIdx.x;
    if (blockIdx.x >= 1024) {
        // ---- ELL fill: 4 consecutive edges per thread, vector loads ----
        const int ge0 = ((blockIdx.x - 1024) * 256 + tid) * 4;   // b*E + e, e%4==0
        const int b = ge0 >> 16, e = ge0 & 0xFFFF;
        const float4 m4 = *(const float4*)&emask[ge0];
        const int4 s4 = *(const int4*)&ei[(size_t)(b * 2) * E + e];
        const int4 t4 = *(const int4*)&ei[(size_t)(b * 2 + 1) * E + e];
        const float mv[4] = {m4.x, m4.y, m4.z, m4.w};
        const int sv[4] = {s4.x, s4.y, s4.z, s4.w};
        const int tv[4] = {t4.x, t4.y, t4.z, t4.w};
        #pragma unroll
        for (int q = 0; q < 4; ++q) {
            if (mv[q] > 0.f) {
                const int r = b * N + tv[q];
                const int p = atomicAdd(&ecnt[r], 1);
                if (p < ELLW)
                    ell[(size_t)r * ELLW + p] = ((unsigned int)f2b(mv[q]) << 16) | (unsigned int)sv[q];
            }
        }
        return;
    }
    const int wv = tid >> 6, lane = tid & 63;
    const int quad = lane >> 4, col = lane & 15;
    const int mg = wv >> 1, nw = wv & 1;
    const int row0 = blockIdx.x * 64;
    bf16x8 fh[2][2], fl[2][2];
    #pragma unroll
    for (int mt = 0; mt < 2; ++mt) {
        const int row = row0 + (mg * 2 + mt) * 16 + col;
        #pragma unroll
        for (int j = 0; j < 2; ++j) {
            const float* src = &feats[(size_t)row * FIN + j * 32 + quad * 8];
            const float4 v0 = *(const float4*)src;
            const float4 v1 = *(const float4*)(src + 4);
            const float fv[8] = {v0.x, v0.y, v0.z, v0.w, v1.x, v1.y, v1.z, v1.w};
            union { bf16x8 v; unsigned short u[8]; } Hh, Ll;
            #pragma unroll
            for (int q = 0; q < 8; ++q) {
                const unsigned short hu = f2b(fv[q]);
                Hh.u[q] = hu;
                Ll.u[q] = f2b(fv[q] - b2f(hu));
            }
            fh[mt][j] = Hh.v;
            fl[mt][j] = Ll.v;
        }
    }
    f32x4 acc[2][4] = {};
    bf16x8 bC[4];
    #pragma unroll
    for (int nt = 0; nt < 4; ++nt)
        bC[nt] = *(const bf16x8*)&Bpi[((size_t)(nw * 4 + nt)) * 512 + lane * 8];
    #pragma unroll
    for (int s = 0; s < INSTEPS; ++s) {
        bf16x8 bN[4];
        if (s + 1 < INSTEPS) {
            #pragma unroll
            for (int nt = 0; nt < 4; ++nt)
                bN[nt] = *(const bf16x8*)&Bpi[((size_t)(s + 1) * 8 + nw * 4 + nt) * 512 + lane * 8];
        }
        const int g = s >> 1, j = s & 1;
        #pragma unroll
        for (int mt = 0; mt < 2; ++mt) {
            const bf16x8 a = (g == 1) ? fl[mt][j] : fh[mt][j];
            #pragma unroll
            for (int nt = 0; nt < 4; ++nt)
                acc[mt][nt] = __builtin_amdgcn_mfma_f32_16x16x32_bf16(a, bC[nt], acc[mt][nt], 0, 0, 0);
        }
        #pragma unroll
        for (int nt = 0; nt < 4; ++nt) bC[nt] = bN[nt];
    }
    #pragma unroll
    for (int nt = 0; nt < 4; ++nt) {
        const int hh = (nw * 4 + nt) * 16 + col;
        const float bv = bias[hh];
        #pragma unroll
        for (int mt = 0; mt < 2; ++mt)
            #pragma unroll
            for (int r = 0; r < 4; ++r) {
                const int row = row0 + (mg * 2 + mt) * 16 + quad * 4 + r;
                xh[(size_t)row * H + hh] = f2b(fmaxf(acc[mt][nt][r] + bv, 0.f));
            }
    }
}

// ---------------- fused gather+layer v2: 64 rows/block, 1024 blocks, full residency ----------------
__global__ __launch_bounds__(256, 4) void k_fused2(const unsigned short* __restrict__ xin,
                                                   unsigned short* __restrict__ xout,
                                                   const int* __restrict__ ecnt,
                                                   const unsigned int* __restrict__ ell,
                                                   const unsigned short* __restrict__ Bp,
                                                   const float* __restrict__ sb,
                                                   const float* __restrict__ nb,
                                                   const float* __restrict__ lng,
                                                   const float* __restrict__ lnb,
                                                   const float* __restrict__ nmask,
                                                   float* __restrict__ part,
                                                   const int last) {
    __shared__ __align__(16) unsigned short bbuf[2][8 * 512];    // 2 x 8 KB (1 k-step each)
    __shared__ __align__(16) unsigned int nh_s[64 * 68];         // 17.4 KB, pitch 68 u32
    __shared__ float lsum[2][64];
    __shared__ float lsq[2][64];
    __shared__ float psum_s[2][H];
    __shared__ float pmax_s[2][H];

    const int tid = threadIdx.x;
    const int wv = tid >> 6, lane = tid & 63;
    const int quad = lane >> 4, col = lane & 15;
    const int u = blockIdx.x;
    const int b = u & 7;
    const int chunk = u >> 3;                     // 0..127
    const int row0 = b * N + chunk * 64;          // batch-pinned to XCD b

    // ---- phase A: gather own 64 rows (wave wv -> local rows wv*16..+15) ----
    {
        const int r0w = row0 + wv * 16;
        int myc = 0;
        if (lane < 16) myc = min(ecnt[r0w + lane], ELLW);
        unsigned int er[8];                       // 16 rows x 32 entries; flat=k*64+lane
        const unsigned int* ebase = ell + (size_t)r0w * ELLW;
        #pragma unroll
        for (int k = 0; k < 8; ++k) er[k] = ebase[k * 64 + lane];
        const unsigned int* xin32 = (const unsigned int*)xin;
        const size_t bbase = (size_t)b * N * 64;
        #pragma unroll
        for (int rr = 0; rr < 16; ++rr) {
            const int cnt = __shfl(myc, rr);
            const int base = (rr & 1) * 32;
            float a0 = 0.f, a1 = 0.f, c = 0.f;
            const int cnt8 = (cnt + 7) & ~7;
            for (int jj = 0; jj < cnt8; jj += 8) {
                #pragma unroll
                for (int q = 0; q < 8; ++q) {
                    const int s = jj + q;
                    const unsigned int pk = __shfl(er[rr >> 1], base + s);
                    const float m = (s < cnt) ? b2f((unsigned short)(pk >> 16)) : 0.f;
                    const unsigned int uu = xin32[bbase + (size_t)(pk & (N - 1)) * 64 + lane];
                    union { unsigned int i; float f; } lo, hi;
                    lo.i = uu << 16;
                    hi.i = uu & 0xFFFF0000u;
                    a0 = fmaf(lo.f, m, a0);
                    a1 = fmaf(hi.f, m, a1);
                    c += m;
                }
            }
            const float inv = 1.f / fmaxf(c, 1.f);
            nh_s[(wv * 16 + rr) * 68 + lane] =
                (unsigned int)f2b(a0 * inv) | ((unsigned int)f2b(a1 * inv) << 16);
        }
    }

    // ---- phase B: MFMA layer ----
    const int mg = (tid >> 6) >> 1, nw = (tid >> 6) & 1;
    size_t abase[2];
    int rloc[2];
    #pragma unroll
    for (int mt = 0; mt < 2; ++mt) {
        rloc[mt] = (mg * 2 + mt) * 16 + col;
        abase[mt] = (size_t)(row0 + rloc[mt]) * H + quad * 8;
    }
    const unsigned short* nh16 = (const unsigned short*)nh_s;   // pitch 136 shorts

    #pragma unroll
    for (int i = 0; i < 2; ++i) {
        const unsigned short* g = Bp + (size_t)(wv * 2 + i) * 512 + lane * 8;
        __builtin_amdgcn_global_load_lds((const AS1 unsigned int*)g,
                                         (AS3 unsigned int*)&bbuf[0][(wv * 2 + i) * 512],
                                         16, 0, 0);
    }
    bf16x8 aC[2];
    #pragma unroll
    for (int mt = 0; mt < 2; ++mt)
        aC[mt] = *(const bf16x8*)&xin[abase[mt]];

    f32x4 acc[2][4] = {};

    #pragma unroll
    for (int s = 0; s < KSTEPS; ++s) {
        __syncthreads();                 // step s staged (also closes phase A at s=0)
        bf16x8 aN[2];
        if (s < KSTEPS - 1) {
            const int s1 = s + 1;
            #pragma unroll
            for (int i = 0; i < 2; ++i) {
                const unsigned short* g = Bp + (size_t)(s1 * 8 + wv * 2 + i) * 512 + lane * 8;
                __builtin_amdgcn_global_load_lds((const AS1 unsigned int*)g,
                                                 (AS3 unsigned int*)&bbuf[s1 & 1][(wv * 2 + i) * 512],
                                                 16, 0, 0);
            }
            if (s1 < 4) {
                #pragma unroll
                for (int mt = 0; mt < 2; ++mt)
                    aN[mt] = *(const bf16x8*)&xin[abase[mt] + (s1 & 3) * 32];
            } else {
                #pragma unroll
                for (int mt = 0; mt < 2; ++mt)
                    aN[mt] = *(const bf16x8*)&nh16[rloc[mt] * 136 + (s1 & 3) * 32 + quad * 8];
            }
        }
        bf16x8 bf[4];
        #pragma unroll
        for (int nt = 0; nt < 4; ++nt)
            bf[nt] = *(const bf16x8*)&bbuf[s & 1][(nw * 4 + nt) * 512 + lane * 8];
        #pragma unroll
        for (int mt = 0; mt < 2; ++mt)
            #pragma unroll
            for (int nt = 0; nt < 4; ++nt)
                acc[mt][nt] = __builtin_amdgcn_mfma_f32_16x16x32_bf16(aC[mt], bf[nt], acc[mt][nt], 0, 0, 0);
        #pragma unroll
        for (int mt = 0; mt < 2; ++mt) aC[mt] = aN[mt];
    }

    // bias + relu (C/D: row = quad*4 + r, col = lane&15; h = (nw*4+nt)*16 + col)
    float sbv[4], nbv[4], gv[4], bbv[4];
    #pragma unroll
    for (int nt = 0; nt < 4; ++nt) {
        const int hh = (nw * 4 + nt) * 16 + col;
        sbv[nt] = sb[hh]; nbv[nt] = nb[hh]; gv[nt] = lng[hh]; bbv[nt] = lnb[hh];
    }
    #pragma unroll
    for (int mt = 0; mt < 2; ++mt)
        #pragma unroll
        for (int nt = 0; nt < 4; ++nt)
            #pragma unroll
            for (int r = 0; r < 4; ++r)
                acc[mt][nt][r] = fmaxf(acc[mt][nt][r] + sbv[nt] + nbv[nt], 0.f);

    // LN partials
    #pragma unroll
    for (int mt = 0; mt < 2; ++mt)
        #pragma unroll
        for (int r = 0; r < 4; ++r) {
            float p = 0.f, q = 0.f;
            #pragma unroll
            for (int nt = 0; nt < 4; ++nt) {
                const float v = acc[mt][nt][r];
                p += v;
                q = fmaf(v, v, q);
            }
            p += __shfl_xor(p, 1);  q += __shfl_xor(q, 1);
            p += __shfl_xor(p, 2);  q += __shfl_xor(q, 2);
            p += __shfl_xor(p, 4);  q += __shfl_xor(q, 4);
            p += __shfl_xor(p, 8);  q += __shfl_xor(q, 8);
            if (col == 0) {
                const int rib = (mg * 2 + mt) * 16 + quad * 4 + r;
                lsum[nw][rib] = p;
                lsq[nw][rib] = q;
            }
        }
    __syncthreads();

    float psum[4] = {0.f, 0.f, 0.f, 0.f};
    float pmax[4] = {-INFINITY, -INFINITY, -INFINITY, -INFINITY};

    #pragma unroll
    for (int mt = 0; mt < 2; ++mt)
        #pragma unroll
        for (int r = 0; r < 4; ++r) {
            const int rib = (mg * 2 + mt) * 16 + quad * 4 + r;
            const int node = row0 + rib;
            const float mu = (lsum[0][rib] + lsum[1][rib]) * (1.f / H);
            const float var = (lsq[0][rib] + lsq[1][rib]) * (1.f / H) - mu * mu;
            const float isd = rsqrtf(var + EPS);
            const float m = nmask[node];
            #pragma unroll
            for (int nt = 0; nt < 4; ++nt) {
                const float y = (fmaf(acc[mt][nt][r] - mu, isd * gv[nt], bbv[nt])) * m;
                if (!last) {
                    xout[(size_t)node * H + (nw * 4 + nt) * 16 + col] = f2b(y);
                } else {
                    psum[nt] += y;
                    pmax[nt] = fmaxf(pmax[nt], (m > 0.f) ? y : -INFINITY);
                }
            }
        }

    if (!last) return;

    #pragma unroll
    for (int nt = 0; nt < 4; ++nt) {
        psum[nt] += __shfl_xor(psum[nt], 16);
        psum[nt] += __shfl_xor(psum[nt], 32);
        pmax[nt] = fmaxf(pmax[nt], __shfl_xor(pmax[nt], 16));
        pmax[nt] = fmaxf(pmax[nt], __shfl_xor(pmax[nt], 32));
    }
    if (quad == 0)
        #pragma unroll
        for (int nt = 0; nt < 4; ++nt) {
            psum_s[mg][(nw * 4 + nt) * 16 + col] = psum[nt];
            pmax_s[mg][(nw * 4 + nt) * 16 + col] = pmax[nt];
        }
    float nv = 0.f;
    if (wv == 0) {
        nv = nmask[row0 + lane];
        nv += __shfl_xor(nv, 1);  nv += __shfl_xor(nv, 2);
        nv += __shfl_xor(nv, 4);  nv += __shfl_xor(nv, 8);
        nv += __shfl_xor(nv, 16); nv += __shfl_xor(nv, 32);
    }
    __syncthreads();
    float* p = part + ((size_t)b * NCHUNK + chunk) * (2 * H + 1);
    if (tid < H) {
        p[tid] = psum_s[0][tid] + psum_s[1][tid];
        p[H + tid] = fmaxf(pmax_s[0][tid], pmax_s[1][tid]);
    }
    if (tid == 0) p[2 * H] = nv;
}

// ---------------- fused pool-reduce + MLP head (1024 threads, 4-way chunk split) ----------------
__global__ __launch_bounds__(1024) void k_tail2(const float* __restrict__ part,
                                                const float* __restrict__ W1, const float* __restrict__ b1,
                                                const float* __restrict__ W2, const float* __restrict__ b2,
                                                float* __restrict__ out) {
    const int b = blockIdx.x, tid = threadIdx.x;
    const int col = tid & 255;
    const int sub = tid >> 8;
    __shared__ float sred[4][2 * H];
    __shared__ float nvl[NCHUNK];
    __shared__ float g[2 * H];
    __shared__ float hid[H];
    {
        float acc = (col < H) ? 0.f : -INFINITY;
        #pragma unroll 8
        for (int c = sub * (NCHUNK / 4); c < (sub + 1) * (NCHUNK / 4); ++c) {
            const float v = part[((size_t)b * NCHUNK + c) * (2 * H + 1) + col];
            acc = (col < H) ? (acc + v) : fmaxf(acc, v);
        }
        sred[sub][col] = acc;
    }
    if (tid < NCHUNK)
        nvl[tid] = part[((size_t)b * NCHUNK + tid) * (2 * H + 1) + 2 * H];
    __syncthreads();
    for (int s = NCHUNK / 2; s > 0; s >>= 1) {
        if (tid < s) nvl[tid] += nvl[tid + s];
        __syncthreads();
    }
    const float nv = fmaxf(nvl[0], 1.f);
    if (tid < 2 * H) {
        if (tid < H)
            g[tid] = (sred[0][tid] + sred[1][tid] + sred[2][tid] + sred[3][tid]) / nv;
        else
            g[tid] = fmaxf(fmaxf(sred[0][tid], sred[1][tid]), fmaxf(sred[2][tid], sred[3][tid]));
    }
    __syncthreads();
    if (tid < H) {
        float a = b1[tid];
        #pragma unroll 8
        for (int k = 0; k < 2 * H; ++k) a = fmaf(g[k], W1[k * H + tid], a);
        hid[tid] = fmaxf(a, 0.f);
    }
    __syncthreads();
    if (tid < OUTD) {
        float a = b2[tid];
        #pragma unroll 8
        for (int k = 0; k < H; ++k) a = fmaf(hid[k], W2[k * OUTD + tid], a);
        out[(size_t)b * OUTD + tid] = a;
    }
}

extern "C" void kernel_launch(void* const* d_in, const int* in_sizes, int n_in,
                              void* d_out, int out_size, void* d_ws, size_t ws_size,
                              hipStream_t stream) {
    const float* feats = (const float*)d_in[0];
    const int*   ei    = (const int*)d_in[1];
    const float* nmask = (const float*)d_in[2];
    const float* emask = (const float*)d_in[3];
    const float* inW   = (const float*)d_in[4];
    const float* inb   = (const float*)d_in[5];
    const float* selfW = (const float*)d_in[6];
    const float* selfb = (const float*)d_in[7];
    const float* neighW= (const float*)d_in[8];
    const float* neighb= (const float*)d_in[9];
    const float* lng   = (const float*)d_in[10];
    const float* lnb   = (const float*)d_in[11];
    const float* W1    = (const float*)d_in[12];
    const float* b1    = (const float*)d_in[13];
    const float* W2    = (const float*)d_in[14];
    const float* b2    = (const float*)d_in[15];
    float* out = (float*)d_out;

    const size_t nxh = (size_t)NNODE * H;
    char* w = (char*)d_ws;
    unsigned short* xA  = (unsigned short*)w;  w += nxh * 2;
    unsigned short* xB  = (unsigned short*)w;  w += nxh * 2;
    unsigned short* Bp  = (unsigned short*)w;  w += (size_t)NLAYER * BPL * 2;
    unsigned short* Bpi = (unsigned short*)w;  w += (size_t)INSTEPS * 8 * 512 * 2;
    float* part = (float*)w;                   w += (size_t)B * NCHUNK * (2 * H + 1) * 4;
    int* ecnt   = (int*)w;                     w += (size_t)NNODE * 4;
    unsigned int* ell = (unsigned int*)w;      w += (size_t)NNODE * ELLW * 4;

    // node 1: prep (weights) + zero ecnt (int4)
    k_prep<<<PREPN + ZBLK, 64, 0, stream>>>(selfW, neighW, inW, Bp, Bpi, ecnt);
    // node 2: inproj || ELL fill (4 edges/thread)
    k_front<<<1024 + FILLB, 256, 0, stream>>>(feats, Bpi, inb, xA, ei, emask, ecnt, ell);
    // nodes 3-5: fused gather+layer, ping-pong xA<->xB; last emits pool partials only
    k_fused2<<<NNODE / 64, 256, 0, stream>>>(xA, xB, ecnt, ell, Bp,
                                             selfb, neighb, lng, lnb, nmask, part, 0);
    k_fused2<<<NNODE / 64, 256, 0, stream>>>(xB, xA, ecnt, ell, Bp + (size_t)1 * BPL,
                                             selfb + H, neighb + H, lng + H, lnb + H,
                                             nmask, part, 0);
    k_fused2<<<NNODE / 64, 256, 0, stream>>>(xA, xB, ecnt, ell, Bp + (size_t)2 * BPL,
                                             selfb + 2 * H, neighb + 2 * H, lng + 2 * H, lnb + 2 * H,
                                             nmask, part, 1);
    // node 6: pool-reduce + MLP head
    k_tail2<<<B, 1024, 0, stream>>>(part, W1, b1, W2, b2, out);
}

// Round 19
// 248.188 us; speedup vs baseline: 1.0585x; 1.0585x over previous
//
#include <hip/hip_runtime.h>
#include <hip/hip_bf16.h>

#define B 8
#define N 8192
#define E 65536
#define FIN 64
#define H 128
#define OUTD 256
#define NLAYER 3
#define EPS 1e-5f
#define NCHUNK 128               // pool chunks per batch (one per 64-row fused block)
#define NNODE (B * N)            // 65536 rows
#define KSTEPS 8                 // 2 groups x 4 k-steps of K=32 (xh*sWhi, nh*nWhi)
#define BPL (KSTEPS * 8 * 512)   // Bp ushort elems per layer
#define INSTEPS 6                // inproj: 3 groups x 2 k-steps (fh*Whi, fl*Whi, fh*Wlo)
#define ELLW 32                  // max incoming edges/node (Poisson(8): P(>32) ~ 2e-11)
#define PREPN (NLAYER * KSTEPS * 8 + INSTEPS * 8)   // 240 prep blocks
#define ZBLK 256                 // ecnt-zero blocks (int4 x 64 lanes x 256 = 65536 ints)

#define AS1 __attribute__((address_space(1)))
#define AS3 __attribute__((address_space(3)))

typedef float f32x4 __attribute__((ext_vector_type(4)));
typedef __bf16 bf16x8 __attribute__((ext_vector_type(8)));

__device__ __forceinline__ float b2f(unsigned short u) {
    union { float f; unsigned int i; } c; c.i = ((unsigned int)u) << 16; return c.f;
}
__device__ __forceinline__ unsigned short f2b(float f) {
    __hip_bfloat16 h = __float2bfloat16(f);          // RTNE
    return *reinterpret_cast<unsigned short*>(&h);
}

// ---------------- weight pre-pack + ecnt zeroing (one node) ----------------
__global__ void k_prep(const float* __restrict__ selfW, const float* __restrict__ neighW,
                       const float* __restrict__ inW,
                       unsigned short* __restrict__ Bp, unsigned short* __restrict__ Bpi,
                       int* __restrict__ ecnt) {
    const int idx = blockIdx.x;
    const int lane = threadIdx.x;
    const int quad = lane >> 4, col = lane & 15;
    if (idx >= PREPN) {
        int4 z; z.x = 0; z.y = 0; z.z = 0; z.w = 0;
        ((int4*)ecnt)[(size_t)(idx - PREPN) * 64 + lane] = z;
        return;
    }
    if (idx < NLAYER * KSTEPS * 8) {
        const int t = idx & 7;
        const int s = (idx >> 3) % KSTEPS;
        const int l = idx / (KSTEPS * 8);
        const float* W = (((s >> 2) == 0) ? selfW : neighW) + (size_t)l * H * H;
        const int n = t * 16 + col;
        unsigned short* dst = Bp + ((size_t)(l * KSTEPS + s) * 8 + t) * 512 + lane * 8;
        #pragma unroll
        for (int j = 0; j < 8; ++j)
            dst[j] = f2b(W[((s & 3) * 32 + quad * 8 + j) * H + n]);
    } else {
        const int idx2 = idx - NLAYER * KSTEPS * 8;
        const int t = idx2 & 7;
        const int s = idx2 >> 3;                     // 0..5
        const bool lo = ((s >> 1) == 2);
        const int n = t * 16 + col;
        unsigned short* dst = Bpi + ((size_t)(s * 8 + t)) * 512 + lane * 8;
        #pragma unroll
        for (int j = 0; j < 8; ++j) {
            const float w = inW[((s & 1) * 32 + quad * 8 + j) * H + n];
            const unsigned short hi = f2b(w);
            dst[j] = lo ? f2b(w - b2f(hi)) : hi;
        }
    }
}

// ---------------- fat kernel: inproj (blocks 0..1023) || ELL fill (blocks 1024..3071, 1 edge/thread) ----------------
__global__ __launch_bounds__(256) void k_front(const float* __restrict__ feats,
                                               const unsigned short* __restrict__ Bpi,
                                               const float* __restrict__ bias,
                                               unsigned short* __restrict__ xh,
                                               const int* __restrict__ ei,
                                               const float* __restrict__ emask,
                                               int* __restrict__ ecnt,
                                               unsigned int* __restrict__ ell) {
    const int tid = threadIdx.x;
    if (blockIdx.x >= 1024) {
        // ---- ELL fill: 1 edge/thread (max TLP; atomic-latency-bound phase) ----
        const int ge = (blockIdx.x - 1024) * 256 + tid;      // b*E + e
        const float m = emask[ge];
        if (m > 0.f) {
            const int b = ge >> 16, e = ge & 0xFFFF;
            const int tgt = ei[(b * 2 + 1) * E + e];
            const int src = ei[(b * 2) * E + e];
            const int r = b * N + tgt;
            const int p = atomicAdd(&ecnt[r], 1);
            if (p < ELLW)
                ell[(size_t)r * ELLW + p] = ((unsigned int)f2b(m) << 16) | (unsigned int)src;
        }
        return;
    }
    const int wv = tid >> 6, lane = tid & 63;
    const int quad = lane >> 4, col = lane & 15;
    const int mg = wv >> 1, nw = wv & 1;
    const int row0 = blockIdx.x * 64;
    bf16x8 fh[2][2], fl[2][2];
    #pragma unroll
    for (int mt = 0; mt < 2; ++mt) {
        const int row = row0 + (mg * 2 + mt) * 16 + col;
        #pragma unroll
        for (int j = 0; j < 2; ++j) {
            const float* src = &feats[(size_t)row * FIN + j * 32 + quad * 8];
            const float4 v0 = *(const float4*)src;
            const float4 v1 = *(const float4*)(src + 4);
            const float fv[8] = {v0.x, v0.y, v0.z, v0.w, v1.x, v1.y, v1.z, v1.w};
            union { bf16x8 v; unsigned short u[8]; } Hh, Ll;
            #pragma unroll
            for (int q = 0; q < 8; ++q) {
                const unsigned short hu = f2b(fv[q]);
                Hh.u[q] = hu;
                Ll.u[q] = f2b(fv[q] - b2f(hu));
            }
            fh[mt][j] = Hh.v;
            fl[mt][j] = Ll.v;
        }
    }
    f32x4 acc[2][4] = {};
    bf16x8 bC[4];
    #pragma unroll
    for (int nt = 0; nt < 4; ++nt)
        bC[nt] = *(const bf16x8*)&Bpi[((size_t)(nw * 4 + nt)) * 512 + lane * 8];
    #pragma unroll
    for (int s = 0; s < INSTEPS; ++s) {
        bf16x8 bN[4];
        if (s + 1 < INSTEPS) {
            #pragma unroll
            for (int nt = 0; nt < 4; ++nt)
                bN[nt] = *(const bf16x8*)&Bpi[((size_t)(s + 1) * 8 + nw * 4 + nt) * 512 + lane * 8];
        }
        const int g = s >> 1, j = s & 1;
        #pragma unroll
        for (int mt = 0; mt < 2; ++mt) {
            const bf16x8 a = (g == 1) ? fl[mt][j] : fh[mt][j];
            #pragma unroll
            for (int nt = 0; nt < 4; ++nt)
                acc[mt][nt] = __builtin_amdgcn_mfma_f32_16x16x32_bf16(a, bC[nt], acc[mt][nt], 0, 0, 0);
        }
        #pragma unroll
        for (int nt = 0; nt < 4; ++nt) bC[nt] = bN[nt];
    }
    #pragma unroll
    for (int nt = 0; nt < 4; ++nt) {
        const int hh = (nw * 4 + nt) * 16 + col;
        const float bv = bias[hh];
        #pragma unroll
        for (int mt = 0; mt < 2; ++mt)
            #pragma unroll
            for (int r = 0; r < 4; ++r) {
                const int row = row0 + (mg * 2 + mt) * 16 + quad * 4 + r;
                xh[(size_t)row * H + hh] = f2b(fmaxf(acc[mt][nt][r] + bv, 0.f));
            }
    }
}

// ---------------- fused gather+layer v2: 64 rows/block, 1024 blocks, full residency ----------------
__global__ __launch_bounds__(256, 4) void k_fused2(const unsigned short* __restrict__ xin,
                                                   unsigned short* __restrict__ xout,
                                                   const int* __restrict__ ecnt,
                                                   const unsigned int* __restrict__ ell,
                                                   const unsigned short* __restrict__ Bp,
                                                   const float* __restrict__ sb,
                                                   const float* __restrict__ nb,
                                                   const float* __restrict__ lng,
                                                   const float* __restrict__ lnb,
                                                   const float* __restrict__ nmask,
                                                   float* __restrict__ part,
                                                   const int last) {
    __shared__ __align__(16) unsigned short bbuf[2][8 * 512];    // 2 x 8 KB (1 k-step each)
    __shared__ __align__(16) unsigned int nh_s[64 * 68];         // 17.4 KB, pitch 68 u32
    __shared__ float lsum[2][64];
    __shared__ float lsq[2][64];
    __shared__ float psum_s[2][H];
    __shared__ float pmax_s[2][H];

    const int tid = threadIdx.x;
    const int wv = tid >> 6, lane = tid & 63;
    const int quad = lane >> 4, col = lane & 15;
    const int u = blockIdx.x;
    const int b = u & 7;
    const int chunk = u >> 3;                     // 0..127
    const int row0 = b * N + chunk * 64;          // batch-pinned to XCD b

    // ---- phase A: gather own 64 rows (wave wv -> local rows wv*16..+15) ----
    {
        const int r0w = row0 + wv * 16;
        int myc = 0;
        if (lane < 16) myc = min(ecnt[r0w + lane], ELLW);
        unsigned int er[8];                       // 16 rows x 32 entries; flat=k*64+lane
        const unsigned int* ebase = ell + (size_t)r0w * ELLW;
        #pragma unroll
        for (int k = 0; k < 8; ++k) er[k] = ebase[k * 64 + lane];
        const unsigned int* xin32 = (const unsigned int*)xin;
        const size_t bbase = (size_t)b * N * 64;
        #pragma unroll
        for (int rr = 0; rr < 16; ++rr) {
            const int cnt = __shfl(myc, rr);
            const int base = (rr & 1) * 32;
            float a0 = 0.f, a1 = 0.f, c = 0.f;
            const int cnt8 = (cnt + 7) & ~7;
            for (int jj = 0; jj < cnt8; jj += 8) {
                #pragma unroll
                for (int q = 0; q < 8; ++q) {
                    const int s = jj + q;
                    const unsigned int pk = __shfl(er[rr >> 1], base + s);
                    const float m = (s < cnt) ? b2f((unsigned short)(pk >> 16)) : 0.f;
                    const unsigned int uu = xin32[bbase + (size_t)(pk & (N - 1)) * 64 + lane];
                    union { unsigned int i; float f; } lo, hi;
                    lo.i = uu << 16;
                    hi.i = uu & 0xFFFF0000u;
                    a0 = fmaf(lo.f, m, a0);
                    a1 = fmaf(hi.f, m, a1);
                    c += m;
                }
            }
            const float inv = 1.f / fmaxf(c, 1.f);
            nh_s[(wv * 16 + rr) * 68 + lane] =
                (unsigned int)f2b(a0 * inv) | ((unsigned int)f2b(a1 * inv) << 16);
        }
    }

    // ---- phase B: MFMA layer ----
    const int mg = (tid >> 6) >> 1, nw = (tid >> 6) & 1;
    size_t abase[2];
    int rloc[2];
    #pragma unroll
    for (int mt = 0; mt < 2; ++mt) {
        rloc[mt] = (mg * 2 + mt) * 16 + col;
        abase[mt] = (size_t)(row0 + rloc[mt]) * H + quad * 8;
    }
    const unsigned short* nh16 = (const unsigned short*)nh_s;   // pitch 136 shorts

    #pragma unroll
    for (int i = 0; i < 2; ++i) {
        const unsigned short* g = Bp + (size_t)(wv * 2 + i) * 512 + lane * 8;
        __builtin_amdgcn_global_load_lds((const AS1 unsigned int*)g,
                                         (AS3 unsigned int*)&bbuf[0][(wv * 2 + i) * 512],
                                         16, 0, 0);
    }
    bf16x8 aC[2];
    #pragma unroll
    for (int mt = 0; mt < 2; ++mt)
        aC[mt] = *(const bf16x8*)&xin[abase[mt]];

    f32x4 acc[2][4] = {};

    #pragma unroll
    for (int s = 0; s < KSTEPS; ++s) {
        __syncthreads();                 // step s staged (also closes phase A at s=0)
        bf16x8 aN[2];
        if (s < KSTEPS - 1) {
            const int s1 = s + 1;
            #pragma unroll
            for (int i = 0; i < 2; ++i) {
                const unsigned short* g = Bp + (size_t)(s1 * 8 + wv * 2 + i) * 512 + lane * 8;
                __builtin_amdgcn_global_load_lds((const AS1 unsigned int*)g,
                                                 (AS3 unsigned int*)&bbuf[s1 & 1][(wv * 2 + i) * 512],
                                                 16, 0, 0);
            }
            if (s1 < 4) {
                #pragma unroll
                for (int mt = 0; mt < 2; ++mt)
                    aN[mt] = *(const bf16x8*)&xin[abase[mt] + (s1 & 3) * 32];
            } else {
                #pragma unroll
                for (int mt = 0; mt < 2; ++mt)
                    aN[mt] = *(const bf16x8*)&nh16[rloc[mt] * 136 + (s1 & 3) * 32 + quad * 8];
            }
        }
        bf16x8 bf[4];
        #pragma unroll
        for (int nt = 0; nt < 4; ++nt)
            bf[nt] = *(const bf16x8*)&bbuf[s & 1][(nw * 4 + nt) * 512 + lane * 8];
        #pragma unroll
        for (int mt = 0; mt < 2; ++mt)
            #pragma unroll
            for (int nt = 0; nt < 4; ++nt)
                acc[mt][nt] = __builtin_amdgcn_mfma_f32_16x16x32_bf16(aC[mt], bf[nt], acc[mt][nt], 0, 0, 0);
        #pragma unroll
        for (int mt = 0; mt < 2; ++mt) aC[mt] = aN[mt];
    }

    // bias + relu (C/D: row = quad*4 + r, col = lane&15; h = (nw*4+nt)*16 + col)
    float sbv[4], nbv[4], gv[4], bbv[4];
    #pragma unroll
    for (int nt = 0; nt < 4; ++nt) {
        const int hh = (nw * 4 + nt) * 16 + col;
        sbv[nt] = sb[hh]; nbv[nt] = nb[hh]; gv[nt] = lng[hh]; bbv[nt] = lnb[hh];
    }
    #pragma unroll
    for (int mt = 0; mt < 2; ++mt)
        #pragma unroll
        for (int nt = 0; nt < 4; ++nt)
            #pragma unroll
            for (int r = 0; r < 4; ++r)
                acc[mt][nt][r] = fmaxf(acc[mt][nt][r] + sbv[nt] + nbv[nt], 0.f);

    // LN partials
    #pragma unroll
    for (int mt = 0; mt < 2; ++mt)
        #pragma unroll
        for (int r = 0; r < 4; ++r) {
            float p = 0.f, q = 0.f;
            #pragma unroll
            for (int nt = 0; nt < 4; ++nt) {
                const float v = acc[mt][nt][r];
                p += v;
                q = fmaf(v, v, q);
            }
            p += __shfl_xor(p, 1);  q += __shfl_xor(q, 1);
            p += __shfl_xor(p, 2);  q += __shfl_xor(q, 2);
            p += __shfl_xor(p, 4);  q += __shfl_xor(q, 4);
            p += __shfl_xor(p, 8);  q += __shfl_xor(q, 8);
            if (col == 0) {
                const int rib = (mg * 2 + mt) * 16 + quad * 4 + r;
                lsum[nw][rib] = p;
                lsq[nw][rib] = q;
            }
        }
    __syncthreads();

    float psum[4] = {0.f, 0.f, 0.f, 0.f};
    float pmax[4] = {-INFINITY, -INFINITY, -INFINITY, -INFINITY};

    #pragma unroll
    for (int mt = 0; mt < 2; ++mt)
        #pragma unroll
        for (int r = 0; r < 4; ++r) {
            const int rib = (mg * 2 + mt) * 16 + quad * 4 + r;
            const int node = row0 + rib;
            const float mu = (lsum[0][rib] + lsum[1][rib]) * (1.f / H);
            const float var = (lsq[0][rib] + lsq[1][rib]) * (1.f / H) - mu * mu;
            const float isd = rsqrtf(var + EPS);
            const float m = nmask[node];
            #pragma unroll
            for (int nt = 0; nt < 4; ++nt) {
                const float y = (fmaf(acc[mt][nt][r] - mu, isd * gv[nt], bbv[nt])) * m;
                if (!last) {
                    xout[(size_t)node * H + (nw * 4 + nt) * 16 + col] = f2b(y);
                } else {
                    psum[nt] += y;
                    pmax[nt] = fmaxf(pmax[nt], (m > 0.f) ? y : -INFINITY);
                }
            }
        }

    if (!last) return;

    #pragma unroll
    for (int nt = 0; nt < 4; ++nt) {
        psum[nt] += __shfl_xor(psum[nt], 16);
        psum[nt] += __shfl_xor(psum[nt], 32);
        pmax[nt] = fmaxf(pmax[nt], __shfl_xor(pmax[nt], 16));
        pmax[nt] = fmaxf(pmax[nt], __shfl_xor(pmax[nt], 32));
    }
    if (quad == 0)
        #pragma unroll
        for (int nt = 0; nt < 4; ++nt) {
            psum_s[mg][(nw * 4 + nt) * 16 + col] = psum[nt];
            pmax_s[mg][(nw * 4 + nt) * 16 + col] = pmax[nt];
        }
    float nv = 0.f;
    if (wv == 0) {
        nv = nmask[row0 + lane];
        nv += __shfl_xor(nv, 1);  nv += __shfl_xor(nv, 2);
        nv += __shfl_xor(nv, 4);  nv += __shfl_xor(nv, 8);
        nv += __shfl_xor(nv, 16); nv += __shfl_xor(nv, 32);
    }
    __syncthreads();
    float* p = part + ((size_t)b * NCHUNK + chunk) * (2 * H + 1);
    if (tid < H) {
        p[tid] = psum_s[0][tid] + psum_s[1][tid];
        p[H + tid] = fmaxf(pmax_s[0][tid], pmax_s[1][tid]);
    }
    if (tid == 0) p[2 * H] = nv;
}

// ---------------- fused pool-reduce + MLP head (1024 threads, 4-way chunk split) ----------------
__global__ __launch_bounds__(1024) void k_tail2(const float* __restrict__ part,
                                                const float* __restrict__ W1, const float* __restrict__ b1,
                                                const float* __restrict__ W2, const float* __restrict__ b2,
                                                float* __restrict__ out) {
    const int b = blockIdx.x, tid = threadIdx.x;
    const int col = tid & 255;
    const int sub = tid >> 8;
    __shared__ float sred[4][2 * H];
    __shared__ float nvl[NCHUNK];
    __shared__ float g[2 * H];
    __shared__ float hid[H];
    {
        float acc = (col < H) ? 0.f : -INFINITY;
        #pragma unroll 8
        for (int c = sub * (NCHUNK / 4); c < (sub + 1) * (NCHUNK / 4); ++c) {
            const float v = part[((size_t)b * NCHUNK + c) * (2 * H + 1) + col];
            acc = (col < H) ? (acc + v) : fmaxf(acc, v);
        }
        sred[sub][col] = acc;
    }
    if (tid < NCHUNK)
        nvl[tid] = part[((size_t)b * NCHUNK + tid) * (2 * H + 1) + 2 * H];
    __syncthreads();
    for (int s = NCHUNK / 2; s > 0; s >>= 1) {
        if (tid < s) nvl[tid] += nvl[tid + s];
        __syncthreads();
    }
    const float nv = fmaxf(nvl[0], 1.f);
    if (tid < 2 * H) {
        if (tid < H)
            g[tid] = (sred[0][tid] + sred[1][tid] + sred[2][tid] + sred[3][tid]) / nv;
        else
            g[tid] = fmaxf(fmaxf(sred[0][tid], sred[1][tid]), fmaxf(sred[2][tid], sred[3][tid]));
    }
    __syncthreads();
    if (tid < H) {
        float a = b1[tid];
        #pragma unroll 8
        for (int k = 0; k < 2 * H; ++k) a = fmaf(g[k], W1[k * H + tid], a);
        hid[tid] = fmaxf(a, 0.f);
    }
    __syncthreads();
    if (tid < OUTD) {
        float a = b2[tid];
        #pragma unroll 8
        for (int k = 0; k < H; ++k) a = fmaf(hid[k], W2[k * OUTD + tid], a);
        out[(size_t)b * OUTD + tid] = a;
    }
}

extern "C" void kernel_launch(void* const* d_in, const int* in_sizes, int n_in,
                              void* d_out, int out_size, void* d_ws, size_t ws_size,
                              hipStream_t stream) {
    const float* feats = (const float*)d_in[0];
    const int*   ei    = (const int*)d_in[1];
    const float* nmask = (const float*)d_in[2];
    const float* emask = (const float*)d_in[3];
    const float* inW   = (const float*)d_in[4];
    const float* inb   = (const float*)d_in[5];
    const float* selfW = (const float*)d_in[6];
    const float* selfb = (const float*)d_in[7];
    const float* neighW= (const float*)d_in[8];
    const float* neighb= (const float*)d_in[9];
    const float* lng   = (const float*)d_in[10];
    const float* lnb   = (const float*)d_in[11];
    const float* W1    = (const float*)d_in[12];
    const float* b1    = (const float*)d_in[13];
    const float* W2    = (const float*)d_in[14];
    const float* b2    = (const float*)d_in[15];
    float* out = (float*)d_out;

    const size_t nxh = (size_t)NNODE * H;
    char* w = (char*)d_ws;
    unsigned short* xA  = (unsigned short*)w;  w += nxh * 2;
    unsigned short* xB  = (unsigned short*)w;  w += nxh * 2;
    unsigned short* Bp  = (unsigned short*)w;  w += (size_t)NLAYER * BPL * 2;
    unsigned short* Bpi = (unsigned short*)w;  w += (size_t)INSTEPS * 8 * 512 * 2;
    float* part = (float*)w;                   w += (size_t)B * NCHUNK * (2 * H + 1) * 4;
    int* ecnt   = (int*)w;                     w += (size_t)NNODE * 4;
    unsigned int* ell = (unsigned int*)w;      w += (size_t)NNODE * ELLW * 4;

    // node 1: prep (weights) + zero ecnt (int4)
    k_prep<<<PREPN + ZBLK, 64, 0, stream>>>(selfW, neighW, inW, Bp, Bpi, ecnt);
    // node 2: inproj || ELL fill (1 edge/thread, max TLP)
    k_front<<<1024 + B * E / 256, 256, 0, stream>>>(feats, Bpi, inb, xA, ei, emask, ecnt, ell);
    // nodes 3-5: fused gather+layer, ping-pong xA<->xB; last emits pool partials only
    k_fused2<<<NNODE / 64, 256, 0, stream>>>(xA, xB, ecnt, ell, Bp,
                                             selfb, neighb, lng, lnb, nmask, part, 0);
    k_fused2<<<NNODE / 64, 256, 0, stream>>>(xB, xA, ecnt, ell, Bp + (size_t)1 * BPL,
                                             selfb + H, neighb + H, lng + H, lnb + H,
                                             nmask, part, 0);
    k_fused2<<<NNODE / 64, 256, 0, stream>>>(xA, xB, ecnt, ell, Bp + (size_t)2 * BPL,
                                             selfb + 2 * H, neighb + 2 * H, lng + 2 * H, lnb + 2 * H,
                                             nmask, part, 1);
    // node 6: pool-reduce + MLP head
    k_tail2<<<B, 1024, 0, stream>>>(part, W1, b1, W2, b2, out);
}